// Round 2
// baseline (997.859 us; speedup 1.0000x reference)
//
#include <hip/hip_runtime.h>
#include <hip/hip_bf16.h>

#define T_ 1024
#define D_ 1024
#define F_ 10240
#define E_ 8
#define CAPX 512          // max tokens tracked per expert (12+ sigma margin)
#define BM 192
#define BN 64
#define BK 32
#define PAD 40            // LDS row stride in bf16 elems (80B) -> conflict-free-minimum b128
#define KSPLIT 4

typedef float f32x4 __attribute__((ext_vector_type(4)));
typedef __bf16 bf16x8 __attribute__((ext_vector_type(8)));
typedef __bf16 bf16x4 __attribute__((ext_vector_type(4)));

#define OFF_LOG ((size_t)T_ * D_)
#define OFF_IDX (OFF_LOG + (size_t)T_ * E_)

__device__ __forceinline__ float gelu_tanh(float x) {
  float u = 0.7978845608028654f * (x + 0.044715f * x * x * x);
  return 0.5f * x * (1.0f + tanhf(u));
}

__global__ void __launch_bounds__(64) k_zero(int* cnt) {
  if (threadIdx.x < E_) cnt[threadIdx.x] = 0;
}

// One block per token: fp64 logits, softmax, argmax, gather row to bf16 Xc,
// zero the out row, write logits + expert index.
__global__ void __launch_bounds__(256) k_router(
    const float* __restrict__ hs, const float* __restrict__ Wr,
    float* __restrict__ dout, float* __restrict__ prob,
    int* __restrict__ cnt, int* __restrict__ tokmap, __bf16* __restrict__ Xc) {
  int tok = blockIdx.x;
  int tid = threadIdx.x;
  const float* x = hs + (size_t)tok * D_;
  f32x4 xv = *(const f32x4*)(x + tid * 4);
  double acc[E_];
#pragma unroll
  for (int e = 0; e < E_; e++) acc[e] = 0.0;
#pragma unroll
  for (int c = 0; c < 4; c++) {
    const f32x4* wr = (const f32x4*)(Wr + (size_t)(tid * 4 + c) * E_);
    f32x4 w0 = wr[0], w1 = wr[1];
    double xd = (double)xv[c];
    acc[0] += xd * (double)w0[0]; acc[1] += xd * (double)w0[1];
    acc[2] += xd * (double)w0[2]; acc[3] += xd * (double)w0[3];
    acc[4] += xd * (double)w1[0]; acc[5] += xd * (double)w1[1];
    acc[6] += xd * (double)w1[2]; acc[7] += xd * (double)w1[3];
  }
#pragma unroll
  for (int e = 0; e < E_; e++) {
#pragma unroll
    for (int m = 1; m < 64; m <<= 1) acc[e] += __shfl_xor(acc[e], m, 64);
  }
  __shared__ double sacc[4][E_];
  __shared__ int sbi, sslot;
  int wid = tid >> 6, lane = tid & 63;
  if (lane == 0) {
#pragma unroll
    for (int e = 0; e < E_; e++) sacc[wid][e] = acc[e];
  }
  __syncthreads();
  if (tid == 0) {
    float lg[E_];
    float mx = -1e30f;
    int bi = 0;
#pragma unroll
    for (int e = 0; e < E_; e++) {
      double s = sacc[0][e] + sacc[1][e] + sacc[2][e] + sacc[3][e];
      lg[e] = (float)s;
      if (lg[e] > mx) { mx = lg[e]; bi = e; }   // strict > keeps first max (numpy tie-break)
    }
    double den = 0.0;
#pragma unroll
    for (int e = 0; e < E_; e++) den += exp((double)lg[e] - (double)mx);
    float p = (float)(1.0 / den);
#pragma unroll
    for (int e = 0; e < E_; e++) dout[OFF_LOG + (size_t)tok * E_ + e] = lg[e];
    dout[OFF_IDX + tok] = (float)bi;
    prob[tok] = p;
    int slot = atomicAdd(&cnt[bi], 1);
    if (slot < CAPX) tokmap[bi * CAPX + slot] = tok;
    sbi = bi; sslot = slot;
  }
  __syncthreads();
  f32x4 z = {0.f, 0.f, 0.f, 0.f};
  *(f32x4*)(dout + (size_t)tok * D_ + tid * 4) = z;   // zero output row for atomics
  int slot = sslot;
  if (slot < CAPX) {
    bf16x4 v;
#pragma unroll
    for (int c = 0; c < 4; c++) v[c] = (__bf16)xv[c];
    *(bf16x4*)(Xc + ((size_t)sbi * CAPX + slot) * D_ + tid * 4) = v;
  }
}

// Grouped GEGLU: per (expert, 64-wide F tile), one 192-row M tile (loop if more).
// Dual MFMA accumulators (X@W0, X@W1) share the A operand.
__global__ void __launch_bounds__(256) k_geglu(
    const float* __restrict__ W0, const float* __restrict__ W1,
    const __bf16* __restrict__ Xc, __bf16* __restrict__ Hc,
    const int* __restrict__ cnt, int capH) {
  int e = blockIdx.y;
  int f0 = blockIdx.x * BN;
  int n_tok = cnt[e];
  if (n_tok > capH) n_tok = capH;
  if (n_tok > CAPX) n_tok = CAPX;
  if (n_tok <= 0) return;
  __shared__ __attribute__((aligned(16))) __bf16 Xs[BM * PAD];
  __shared__ __attribute__((aligned(16))) __bf16 W0s[BN * PAD];
  __shared__ __attribute__((aligned(16))) __bf16 W1s[BN * PAD];
  int tid = threadIdx.x;
  int lane = tid & 63, wid = tid >> 6;
  int wm = wid >> 1, wn = wid & 1;
  int nn = tid & 63;
  int kb = (tid >> 6) * 8;
  const size_t WB = (size_t)e * D_ * F_;
  const __bf16* xbase = Xc + (size_t)e * CAPX * D_;

  for (int m0 = 0; m0 < n_tok; m0 += BM) {
    f32x4 acc0[6][2], acc1[6][2];
    f32x4 z = {0.f, 0.f, 0.f, 0.f};
#pragma unroll
    for (int mf = 0; mf < 6; mf++)
#pragma unroll
      for (int nf = 0; nf < 2; nf++) { acc0[mf][nf] = z; acc1[mf][nf] = z; }

    for (int k0 = 0; k0 < D_; k0 += BK) {
      __syncthreads();
      // stage X tile [192][32] bf16 (already bf16, compact rows)
#pragma unroll
      for (int i = 0; i < 3; i++) {
        int c = tid + i * 256;
        int row = c >> 2, seg = c & 3;
        int gr = m0 + row;
        if (gr >= CAPX) gr = CAPX - 1;           // pad rows: garbage ok, masked at store
        bf16x8 v = *(const bf16x8*)(xbase + (size_t)gr * D_ + k0 + seg * 8);
        *(bf16x8*)(Xs + row * PAD + seg * 8) = v;
      }
      // stage W0/W1 tiles transposed: [n][k] k-contiguous, via column-strided
      // coalesced loads (each instr = 64 consecutive floats, 256B)
      {
        const float* p0 = W0 + WB + (size_t)(k0 + kb) * F_ + f0 + nn;
        const float* p1 = W1 + WB + (size_t)(k0 + kb) * F_ + f0 + nn;
        bf16x8 v0, v1;
#pragma unroll
        for (int i = 0; i < 8; i++) {
          v0[i] = (__bf16)p0[(size_t)i * F_];
          v1[i] = (__bf16)p1[(size_t)i * F_];
        }
        *(bf16x8*)(W0s + nn * PAD + kb) = v0;
        *(bf16x8*)(W1s + nn * PAD + kb) = v1;
      }
      __syncthreads();
      int kg = (lane >> 4) * 8;
      int ar = lane & 15;
      bf16x8 a[6];
#pragma unroll
      for (int mf = 0; mf < 6; mf++)
        a[mf] = *(const bf16x8*)(Xs + (wm * 96 + mf * 16 + ar) * PAD + kg);
#pragma unroll
      for (int nf = 0; nf < 2; nf++) {
        bf16x8 b0 = *(const bf16x8*)(W0s + (wn * 32 + nf * 16 + ar) * PAD + kg);
        bf16x8 b1 = *(const bf16x8*)(W1s + (wn * 32 + nf * 16 + ar) * PAD + kg);
#pragma unroll
        for (int mf = 0; mf < 6; mf++) {
          acc0[mf][nf] = __builtin_amdgcn_mfma_f32_16x16x32_bf16(a[mf], b0, acc0[mf][nf], 0, 0, 0);
          acc1[mf][nf] = __builtin_amdgcn_mfma_f32_16x16x32_bf16(a[mf], b1, acc1[mf][nf], 0, 0, 0);
        }
      }
    }
    // epilogue: C/D layout col=lane&15, row=(lane>>4)*4+reg (verified m89/m91)
    int rq = (lane >> 4) * 4;
    int cl = lane & 15;
#pragma unroll
    for (int mf = 0; mf < 6; mf++) {
#pragma unroll
      for (int q = 0; q < 4; q++) {
        int row = m0 + wm * 96 + mf * 16 + rq + q;
        if (row < n_tok) {
#pragma unroll
          for (int nf = 0; nf < 2; nf++) {
            float h = gelu_tanh(acc0[mf][nf][q]) * acc1[mf][nf][q];
            Hc[((size_t)e * capH + row) * F_ + f0 + wn * 32 + nf * 16 + cl] = (__bf16)h;
          }
        }
      }
    }
  }
}

// Down-proj with split-K=4: out[tok] += prob[tok] * (H @ Wo[e]) via f32 atomics.
__global__ void __launch_bounds__(256) k_down(
    const float* __restrict__ Wo, const __bf16* __restrict__ Hc,
    const int* __restrict__ cnt, const int* __restrict__ tokmap,
    const float* __restrict__ prob, float* __restrict__ out, int capH) {
  int e = blockIdx.y;
  int n0 = blockIdx.x * BN;
  int kbeg = blockIdx.z * (F_ / KSPLIT);
  int kend = kbeg + F_ / KSPLIT;
  int n_tok = cnt[e];
  if (n_tok > capH) n_tok = capH;
  if (n_tok > CAPX) n_tok = CAPX;
  if (n_tok <= 0) return;
  __shared__ __attribute__((aligned(16))) __bf16 Hs[BM * PAD];
  __shared__ __attribute__((aligned(16))) __bf16 Wos[BN * PAD];
  int tid = threadIdx.x;
  int lane = tid & 63, wid = tid >> 6;
  int wm = wid >> 1, wn = wid & 1;
  int nn = tid & 63;
  int kb = (tid >> 6) * 8;
  const size_t WB = (size_t)e * F_ * D_;
  const __bf16* hbase = Hc + (size_t)e * capH * F_;

  for (int m0 = 0; m0 < n_tok; m0 += BM) {
    f32x4 acc[6][2];
    f32x4 z = {0.f, 0.f, 0.f, 0.f};
#pragma unroll
    for (int mf = 0; mf < 6; mf++)
#pragma unroll
      for (int nf = 0; nf < 2; nf++) acc[mf][nf] = z;

    for (int k0 = kbeg; k0 < kend; k0 += BK) {
      __syncthreads();
#pragma unroll
      for (int i = 0; i < 3; i++) {
        int c = tid + i * 256;
        int row = c >> 2, seg = c & 3;
        int gr = m0 + row;
        if (gr >= capH) gr = capH - 1;
        bf16x8 v = *(const bf16x8*)(hbase + (size_t)gr * F_ + k0 + seg * 8);
        *(bf16x8*)(Hs + row * PAD + seg * 8) = v;
      }
      {
        const float* p0 = Wo + WB + (size_t)(k0 + kb) * D_ + n0 + nn;
        bf16x8 v0;
#pragma unroll
        for (int i = 0; i < 8; i++) v0[i] = (__bf16)p0[(size_t)i * D_];
        *(bf16x8*)(Wos + nn * PAD + kb) = v0;
      }
      __syncthreads();
      int kg = (lane >> 4) * 8;
      int ar = lane & 15;
      bf16x8 a[6];
#pragma unroll
      for (int mf = 0; mf < 6; mf++)
        a[mf] = *(const bf16x8*)(Hs + (wm * 96 + mf * 16 + ar) * PAD + kg);
#pragma unroll
      for (int nf = 0; nf < 2; nf++) {
        bf16x8 b = *(const bf16x8*)(Wos + (wn * 32 + nf * 16 + ar) * PAD + kg);
#pragma unroll
        for (int mf = 0; mf < 6; mf++)
          acc[mf][nf] = __builtin_amdgcn_mfma_f32_16x16x32_bf16(a[mf], b, acc[mf][nf], 0, 0, 0);
      }
    }
    int rq = (lane >> 4) * 4;
    int cl = lane & 15;
#pragma unroll
    for (int mf = 0; mf < 6; mf++) {
#pragma unroll
      for (int q = 0; q < 4; q++) {
        int row = m0 + wm * 96 + mf * 16 + rq + q;
        if (row < n_tok) {
          int tok = tokmap[e * CAPX + row];
          float p = prob[tok];
#pragma unroll
          for (int nf = 0; nf < 2; nf++) {
            __hip_atomic_fetch_add(
                &out[(size_t)tok * D_ + n0 + wn * 32 + nf * 16 + cl],
                p * acc[mf][nf][q], __ATOMIC_RELAXED, __HIP_MEMORY_SCOPE_AGENT);
          }
        }
      }
    }
  }
}

extern "C" void kernel_launch(void* const* d_in, const int* in_sizes, int n_in,
                              void* d_out, int out_size, void* d_ws, size_t ws_size,
                              hipStream_t stream) {
  const float* hs = (const float*)d_in[0];
  const float* Wr = (const float*)d_in[1];
  const float* W0 = (const float*)d_in[2];
  const float* W1 = (const float*)d_in[3];
  const float* Wo = (const float*)d_in[4];
  float* out = (float*)d_out;
  char* ws = (char*)d_ws;

  int* cnt = (int*)(ws + 0);                    // 32 B
  float* prob = (float*)(ws + 1024);            // 4 KB
  int* tokmap = (int*)(ws + 8192);              // 8*CAPX*4 = 16 KB
  __bf16* Xc = (__bf16*)(ws + 65536);           // 8*512*1024*2 = 8 MB
  size_t hcoff = 65536 + (size_t)E_ * CAPX * D_ * 2;
  size_t avail = ws_size > hcoff ? (ws_size - hcoff) : 0;
  int capH = (int)(avail / ((size_t)E_ * F_ * 2));
  if (capH > CAPX) capH = CAPX;
  if (capH < 1) capH = 1;
  __bf16* Hc = (__bf16*)(ws + hcoff);

  hipLaunchKernelGGL(k_zero, dim3(1), dim3(64), 0, stream, cnt);
  hipLaunchKernelGGL(k_router, dim3(T_), dim3(256), 0, stream,
                     hs, Wr, out, prob, cnt, tokmap, Xc);
  hipLaunchKernelGGL(k_geglu, dim3(F_ / BN, E_), dim3(256), 0, stream,
                     W0, W1, Xc, Hc, cnt, capH);
  hipLaunchKernelGGL(k_down, dim3(D_ / BN, E_, KSPLIT), dim3(256), 0, stream,
                     Wo, Hc, cnt, tokmap, prob, out, capH);
}